// Round 1
// baseline (492.223 us; speedup 1.0000x reference)
//
#include <hip/hip_runtime.h>
#include <math.h>

#define HID 2048
#define TOKENS 4096   // B*T
#define TT 2048       // T
#define BB 2          // B
#define WELEM 4194304 // 2048*2048

typedef unsigned short u16;
typedef __bf16 bf16x8 __attribute__((ext_vector_type(8)));
typedef float f32x4 __attribute__((ext_vector_type(4)));

__device__ inline float sigm(float x) { return 1.0f / (1.0f + expf(-x)); }
// exact for small integers (|v| <= 256) and +-1: bf16 truncation of f32 bits
__device__ inline u16 f2bf(float v) { return (u16)(__float_as_uint(v) >> 16); }

__device__ inline float wred_sum(float v) {
#pragma unroll
  for (int o = 32; o > 0; o >>= 1) v += __shfl_down(v, o);
  return v;
}
__device__ inline float wred_max(float v) {
#pragma unroll
  for (int o = 32; o > 0; o >>= 1) v = fmaxf(v, __shfl_down(v, o));
  return v;
}
__device__ inline double wred_sumd(double v) {
#pragma unroll
  for (int o = 32; o > 0; o >>= 1) v += __shfl_down(v, o);
  return v;
}

// ---------------- K1: mean(|w|) for the 4 weights, f64 accumulation -------
__global__ __launch_bounds__(256) void absmean_kernel(
    const float* __restrict__ w0, const float* __restrict__ w1,
    const float* __restrict__ w2, const float* __restrict__ w3,
    double* __restrict__ wsum) {
  int widx = blockIdx.x >> 9;      // 512 blocks per matrix
  int blk = blockIdx.x & 511;      // 8192 elems per block
  const float* w = widx == 0 ? w0 : widx == 1 ? w1 : widx == 2 ? w2 : w3;
  size_t base = (size_t)blk * 8192;
  double acc = 0.0;
#pragma unroll
  for (int r = 0; r < 8; ++r) {
    float4 v = *(const float4*)&w[base + (size_t)(r * 256 + threadIdx.x) * 4];
    acc += (double)fabsf(v.x) + (double)fabsf(v.y) + (double)fabsf(v.z) +
           (double)fabsf(v.w);
  }
  acc = wred_sumd(acc);
  __shared__ double sh[4];
  int tid = threadIdx.x;
  if ((tid & 63) == 0) sh[tid >> 6] = acc;
  __syncthreads();
  if (tid == 0) atomicAdd(&wsum[widx], (sh[0] + sh[1]) + (sh[2] + sh[3]));
}

// ---------------- K2: ternary-quantize one weight matrix to bf16 ----------
__global__ __launch_bounds__(256) void wquant_kernel(
    const float* __restrict__ w, const double* __restrict__ wsum, int widx,
    u16* __restrict__ wq) {
  double mean = wsum[widx] * (1.0 / (double)WELEM);
  float s = (float)(1.0 / fmax(mean, 1e-5));
  size_t base = (size_t)blockIdx.x * 2048 + (size_t)threadIdx.x * 8;
#pragma unroll
  for (int r = 0; r < 2; ++r) {
    float4 v = *(const float4*)&w[base + r * 4];
    u16 q[4];
    float vv[4] = {v.x, v.y, v.z, v.w};
#pragma unroll
    for (int j = 0; j < 4; ++j) {
      float q1 = rintf(vv[j] * s);
      q1 = fminf(fmaxf(q1, -1.0f), 1.0f);
      q[j] = f2bf(q1);
    }
    *(ushort4*)&wq[base + r * 4] = make_ushort4(q[0], q[1], q[2], q[3]);
  }
}

// ---------------- K3: per-token RMSNorm + 8-bit fake quant -> bf16 ints ---
__global__ __launch_bounds__(256) void rmsquant_kernel(
    const float* __restrict__ X, const float* __restrict__ nw,
    u16* __restrict__ Xq, float* __restrict__ inv_s) {
  int tok = blockIdx.x;
  int tid = threadIdx.x;
  const float* xrow = X + (size_t)tok * HID;
  int c0 = tid * 8;
  float x[8];
  *(float4*)&x[0] = *(const float4*)&xrow[c0];
  *(float4*)&x[4] = *(const float4*)&xrow[c0 + 4];
  float ss = 0.0f;
#pragma unroll
  for (int j = 0; j < 8; ++j) ss += x[j] * x[j];
  __shared__ float sh[4];
  float v = wred_sum(ss);
  if ((tid & 63) == 0) sh[tid >> 6] = v;
  __syncthreads();
  float tot = (sh[0] + sh[1]) + (sh[2] + sh[3]);
  float rstd = (float)(1.0 / sqrt((double)(tot * (1.0f / HID)) + 1e-8));
  float y[8];
  float amax = 0.0f;
#pragma unroll
  for (int j = 0; j < 8; ++j) {
    y[j] = x[j] * rstd * nw[c0 + j];
    amax = fmaxf(amax, fabsf(y[j]));
  }
  __syncthreads();  // protect sh reuse
  v = wred_max(amax);
  if ((tid & 63) == 0) sh[tid >> 6] = v;
  __syncthreads();
  float am = fmaxf(fmaxf(fmaxf(sh[0], sh[1]), fmaxf(sh[2], sh[3])), 1e-5f);
  float s = 127.0f / am;
  u16 q[8];
#pragma unroll
  for (int j = 0; j < 8; ++j) {
    float qq = rintf(y[j] * s);
    qq = fminf(fmaxf(qq, -128.0f), 127.0f);
    q[j] = f2bf(qq);
  }
  *(ushort4*)&Xq[(size_t)tok * HID + c0] = make_ushort4(q[0], q[1], q[2], q[3]);
  *(ushort4*)&Xq[(size_t)tok * HID + c0 + 4] =
      make_ushort4(q[4], q[5], q[6], q[7]);
  if (tid == 0) inv_s[tok] = am * (1.0f / 127.0f);
}

// ---------------- K4: bf16 MFMA GEMM, out[m,n] = sum_k A[m,k]*W[n,k] ------
// MODE 0: out = sigmoid(v)   (f gate)
// MODE 1: out = v*sigm(v)*(1-F)  (i, fused silu*(1-f))
// MODE 2: out = v            (g raw / final projection)
template <int MODE>
__global__ __launch_bounds__(256) void gemm_kernel(
    const u16* __restrict__ Aq, const u16* __restrict__ Wq,
    const float* __restrict__ inv_s, const double* __restrict__ wsum, int widx,
    const float* __restrict__ Fbuf, float* __restrict__ Out) {
  const int tid = threadIdx.x;
  const int m0 = blockIdx.y * 128, n0 = blockIdx.x * 128;
  __shared__ __align__(16) u16 As[128][40];
  __shared__ __align__(16) u16 Bs[128][40];
  float wscale = (float)fmax(wsum[widx] * (1.0 / (double)WELEM), 1e-5);

  const int wave = tid >> 6, lane = tid & 63;
  const int wm = wave >> 1, wn = wave & 1;
  const int lrow = lane & 15, lk = (lane >> 4) * 8;

  f32x4 acc[4][4];
#pragma unroll
  for (int i = 0; i < 4; ++i)
#pragma unroll
    for (int j = 0; j < 4; ++j)
#pragma unroll
      for (int r = 0; r < 4; ++r) acc[i][j][r] = 0.0f;

  for (int k0 = 0; k0 < HID; k0 += 32) {
    __syncthreads();
#pragma unroll
    for (int rep = 0; rep < 2; ++rep) {
      int L = tid + rep * 256;
      int row = L >> 2, ch = (L & 3) * 8;
      *(uint4*)&As[row][ch] =
          *(const uint4*)&Aq[(size_t)(m0 + row) * HID + k0 + ch];
      *(uint4*)&Bs[row][ch] =
          *(const uint4*)&Wq[(size_t)(n0 + row) * HID + k0 + ch];
    }
    __syncthreads();
    bf16x8 af[4], bfr[4];
#pragma unroll
    for (int i = 0; i < 4; ++i) {
      af[i] = *(const bf16x8*)&As[wm * 64 + i * 16 + lrow][lk];
      bfr[i] = *(const bf16x8*)&Bs[wn * 64 + i * 16 + lrow][lk];
    }
#pragma unroll
    for (int i = 0; i < 4; ++i)
#pragma unroll
      for (int j = 0; j < 4; ++j)
        acc[i][j] = __builtin_amdgcn_mfma_f32_16x16x32_bf16(af[i], bfr[j],
                                                            acc[i][j], 0, 0, 0);
  }

#pragma unroll
  for (int i = 0; i < 4; ++i) {
    int rbase = m0 + wm * 64 + i * 16 + (lane >> 4) * 4;
#pragma unroll
    for (int j = 0; j < 4; ++j) {
      int col = n0 + wn * 64 + j * 16 + lrow;
#pragma unroll
      for (int r = 0; r < 4; ++r) {
        int row = rbase + r;
        float v = acc[i][j][r] * inv_s[row] * wscale;
        size_t oidx = (size_t)row * HID + col;
        if (MODE == 0) {
          Out[oidx] = sigm(v);
        } else if (MODE == 1) {
          float f = Fbuf[oidx];
          Out[oidx] = v * sigm(v) * (1.0f - f);
        } else {
          Out[oidx] = v;
        }
      }
    }
  }
}

// ---------------- K5: sequential scan h = f*h + i over T ------------------
__global__ __launch_bounds__(256) void scan_kernel(const float* __restrict__ F,
                                                   float* __restrict__ IO) {
  int g = blockIdx.x * 256 + threadIdx.x;  // 0..4095 = B*HID
  int b = g >> 11, c = g & 2047;
  size_t base = (size_t)b * TT * HID + c;
  float h = 0.0f;
#pragma unroll 8
  for (int t = 0; t < TT; ++t) {
    size_t idx = base + (size_t)t * HID;
    h = fmaf(F[idx], h, IO[idx]);
    IO[idx] = h;
  }
}

// ---------------- K6: o = rms(g,gn_w,1e-5) * o * sigmoid(o) ---------------
__global__ __launch_bounds__(256) void combine_kernel(
    const float* __restrict__ G, const float* __restrict__ gnw,
    float* __restrict__ O) {
  int tok = blockIdx.x;
  int tid = threadIdx.x;
  const float* grow = G + (size_t)tok * HID;
  float* orow = O + (size_t)tok * HID;
  int c0 = tid * 8;
  float g[8];
  *(float4*)&g[0] = *(const float4*)&grow[c0];
  *(float4*)&g[4] = *(const float4*)&grow[c0 + 4];
  float ss = 0.0f;
#pragma unroll
  for (int j = 0; j < 8; ++j) ss += g[j] * g[j];
  __shared__ float sh[4];
  float v = wred_sum(ss);
  if ((tid & 63) == 0) sh[tid >> 6] = v;
  __syncthreads();
  float tot = (sh[0] + sh[1]) + (sh[2] + sh[3]);
  float rstd = (float)(1.0 / sqrt((double)(tot * (1.0f / HID)) + 1e-5));
  float o[8];
  *(float4*)&o[0] = *(const float4*)&orow[c0];
  *(float4*)&o[4] = *(const float4*)&orow[c0 + 4];
#pragma unroll
  for (int j = 0; j < 8; ++j) {
    float on = g[j] * rstd * gnw[c0 + j] * o[j] * sigm(o[j]);
    o[j] = on;
  }
  *(float4*)&orow[c0] = *(const float4*)&o[0];
  *(float4*)&orow[c0 + 4] = *(const float4*)&o[4];
}

extern "C" void kernel_launch(void* const* d_in, const int* in_sizes, int n_in,
                              void* d_out, int out_size, void* d_ws,
                              size_t ws_size, hipStream_t stream) {
  const float* hs = (const float*)d_in[0];
  const float* w_i = (const float*)d_in[1];
  const float* w_f = (const float*)d_in[2];
  const float* w_g = (const float*)d_in[3];
  const float* w_o = (const float*)d_in[4];
  const float* n_i = (const float*)d_in[5];
  const float* n_f = (const float*)d_in[6];
  const float* n_g = (const float*)d_in[7];
  const float* n_o = (const float*)d_in[8];
  const float* gn_w = (const float*)d_in[9];
  float* Out = (float*)d_out;

  char* ws = (char*)d_ws;
  // layout (bytes): WQb 8,388,608 | XQ 16,777,216 | F 33,554,432 | invs 16,384 | wsum 32
  u16* WQb = (u16*)ws;
  u16* XQ = (u16*)(ws + 8388608);
  float* F = (float*)(ws + 25165824);
  float* G = F;  // alias: F dead after scan, G computed after scan
  float* invs = (float*)(ws + 58720256);
  double* wsum = (double*)(ws + 58736640);

  hipMemsetAsync(wsum, 0, 4 * sizeof(double), stream);
  absmean_kernel<<<2048, 256, 0, stream>>>(w_i, w_f, w_g, w_o, wsum);

  dim3 ggrid(HID / 128, TOKENS / 128);

  // f = sigmoid(bitlinear(hs, w_f, n_f))
  wquant_kernel<<<2048, 256, 0, stream>>>(w_f, wsum, 1, WQb);
  rmsquant_kernel<<<TOKENS, 256, 0, stream>>>(hs, n_f, XQ, invs);
  gemm_kernel<0><<<ggrid, 256, 0, stream>>>(XQ, WQb, invs, wsum, 1, nullptr, F);

  // i = silu(bitlinear(hs, w_i, n_i)) * (1 - f)   -> Out
  wquant_kernel<<<2048, 256, 0, stream>>>(w_i, wsum, 0, WQb);
  rmsquant_kernel<<<TOKENS, 256, 0, stream>>>(hs, n_i, XQ, invs);
  gemm_kernel<1><<<ggrid, 256, 0, stream>>>(XQ, WQb, invs, wsum, 0, F, Out);

  // o_t = f_t * o_{t-1} + i_t   (in-place in Out)
  scan_kernel<<<16, 256, 0, stream>>>(F, Out);

  // g = bitlinear(hs, w_g, n_g)  -> G (aliases F)
  wquant_kernel<<<2048, 256, 0, stream>>>(w_g, wsum, 2, WQb);
  rmsquant_kernel<<<TOKENS, 256, 0, stream>>>(hs, n_g, XQ, invs);
  gemm_kernel<2><<<ggrid, 256, 0, stream>>>(XQ, WQb, invs, wsum, 2, nullptr, G);

  // o = rms(g, gn_w, 1e-5) * o * sigmoid(o)
  combine_kernel<<<TOKENS, 256, 0, stream>>>(G, gn_w, Out);

  // out = bitlinear(o, w_o, n_o)  (rmsquant reads Out, gemm rewrites Out)
  wquant_kernel<<<2048, 256, 0, stream>>>(w_o, wsum, 3, WQb);
  rmsquant_kernel<<<TOKENS, 256, 0, stream>>>(Out, n_o, XQ, invs);
  gemm_kernel<2><<<ggrid, 256, 0, stream>>>(XQ, WQb, invs, wsum, 3, nullptr,
                                            Out);
}

// Round 2
// 352.171 us; speedup vs baseline: 1.3977x; 1.3977x over previous
//
#include <hip/hip_runtime.h>
#include <math.h>

#define HID 2048
#define TOKENS 4096   // B*T
#define TT 2048       // T
#define NCH 4096      // B*HID independent scan channels
#define NC 32         // scan chunks along T
#define CL 64         // chunk length = TT/NC
#define WELEM 4194304 // 2048*2048

typedef unsigned short u16;
typedef __bf16 bf16x8 __attribute__((ext_vector_type(8)));
typedef float f32x4 __attribute__((ext_vector_type(4)));

__device__ inline float sigm(float x) { return 1.0f / (1.0f + expf(-x)); }
// exact for small integers (|v| <= 256): bf16 truncation of f32 bits
__device__ inline u16 f2bf(float v) { return (u16)(__float_as_uint(v) >> 16); }

__device__ inline float wred_sum(float v) {
#pragma unroll
  for (int o = 32; o > 0; o >>= 1) v += __shfl_down(v, o);
  return v;
}
__device__ inline float wred_max(float v) {
#pragma unroll
  for (int o = 32; o > 0; o >>= 1) v = fmaxf(v, __shfl_down(v, o));
  return v;
}
__device__ inline double wred_sumd(double v) {
#pragma unroll
  for (int o = 32; o > 0; o >>= 1) v += __shfl_down(v, o);
  return v;
}

// async global->LDS, 16B per lane; LDS dest = wave-uniform base + lane*16
__device__ __forceinline__ void gl_lds16(const void* g, void* l) {
  __builtin_amdgcn_global_load_lds(
      (__attribute__((address_space(1))) void*)(void*)g,
      (__attribute__((address_space(3))) void*)l, 16, 0, 0);
}

// ---------------- K1: mean(|w|) for the 4 weights, f64 accumulation -------
__global__ __launch_bounds__(256) void absmean_kernel(
    const float* __restrict__ w0, const float* __restrict__ w1,
    const float* __restrict__ w2, const float* __restrict__ w3,
    double* __restrict__ wsum) {
  int widx = blockIdx.x >> 9;
  int blk = blockIdx.x & 511;
  const float* w = widx == 0 ? w0 : widx == 1 ? w1 : widx == 2 ? w2 : w3;
  size_t base = (size_t)blk * 8192;
  double acc = 0.0;
#pragma unroll
  for (int r = 0; r < 8; ++r) {
    float4 v = *(const float4*)&w[base + (size_t)(r * 256 + threadIdx.x) * 4];
    acc += (double)fabsf(v.x) + (double)fabsf(v.y) + (double)fabsf(v.z) +
           (double)fabsf(v.w);
  }
  acc = wred_sumd(acc);
  __shared__ double sh[4];
  int tid = threadIdx.x;
  if ((tid & 63) == 0) sh[tid >> 6] = acc;
  __syncthreads();
  if (tid == 0) atomicAdd(&wsum[widx], (sh[0] + sh[1]) + (sh[2] + sh[3]));
}

// ---------------- K2: ternary-quantize one weight matrix to bf16 ----------
__global__ __launch_bounds__(256) void wquant_kernel(
    const float* __restrict__ w, const double* __restrict__ wsum, int widx,
    u16* __restrict__ wq) {
  double mean = wsum[widx] * (1.0 / (double)WELEM);
  float s = (float)(1.0 / fmax(mean, 1e-5));
  size_t base = (size_t)blockIdx.x * 2048 + (size_t)threadIdx.x * 8;
#pragma unroll
  for (int r = 0; r < 2; ++r) {
    float4 v = *(const float4*)&w[base + r * 4];
    u16 q[4];
    float vv[4] = {v.x, v.y, v.z, v.w};
#pragma unroll
    for (int j = 0; j < 4; ++j) {
      float q1 = rintf(vv[j] * s);
      q1 = fminf(fmaxf(q1, -1.0f), 1.0f);
      q[j] = f2bf(q1);
    }
    *(ushort4*)&wq[base + r * 4] = make_ushort4(q[0], q[1], q[2], q[3]);
  }
}

// ---------------- K3: per-token RMSNorm + 8-bit fake quant -> bf16 ints ---
__global__ __launch_bounds__(256) void rmsquant_kernel(
    const float* __restrict__ X, const float* __restrict__ nw,
    u16* __restrict__ Xq, float* __restrict__ inv_s) {
  int tok = blockIdx.x;
  int tid = threadIdx.x;
  const float* xrow = X + (size_t)tok * HID;
  int c0 = tid * 8;
  float x[8];
  *(float4*)&x[0] = *(const float4*)&xrow[c0];
  *(float4*)&x[4] = *(const float4*)&xrow[c0 + 4];
  float ss = 0.0f;
#pragma unroll
  for (int j = 0; j < 8; ++j) ss += x[j] * x[j];
  __shared__ float sh[4];
  float v = wred_sum(ss);
  if ((tid & 63) == 0) sh[tid >> 6] = v;
  __syncthreads();
  float tot = (sh[0] + sh[1]) + (sh[2] + sh[3]);
  float rstd = (float)(1.0 / sqrt((double)(tot * (1.0f / HID)) + 1e-8));
  float y[8];
  float amax = 0.0f;
#pragma unroll
  for (int j = 0; j < 8; ++j) {
    y[j] = x[j] * rstd * nw[c0 + j];
    amax = fmaxf(amax, fabsf(y[j]));
  }
  __syncthreads();
  v = wred_max(amax);
  if ((tid & 63) == 0) sh[tid >> 6] = v;
  __syncthreads();
  float am = fmaxf(fmaxf(fmaxf(sh[0], sh[1]), fmaxf(sh[2], sh[3])), 1e-5f);
  float s = 127.0f / am;
  u16 q[8];
#pragma unroll
  for (int j = 0; j < 8; ++j) {
    float qq = rintf(y[j] * s);
    qq = fminf(fmaxf(qq, -128.0f), 127.0f);
    q[j] = f2bf(qq);
  }
  *(ushort4*)&Xq[(size_t)tok * HID + c0] = make_ushort4(q[0], q[1], q[2], q[3]);
  *(ushort4*)&Xq[(size_t)tok * HID + c0 + 4] =
      make_ushort4(q[4], q[5], q[6], q[7]);
  if (tid == 0) inv_s[tok] = am * (1.0f / 127.0f);
}

// ---------------- K4: bf16 MFMA GEMM (m97 structure: global_load_lds) -----
// out[m,n] = sum_k A[m,k]*W[n,k]
// MODE 0: out = sigmoid(v); MODE 1: out = v*sigm(v)*(1-F); MODE 2: out = v
template <int MODE>
__global__ __launch_bounds__(256) void gemm_kernel(
    const u16* __restrict__ Aq, const u16* __restrict__ Wq,
    const float* __restrict__ inv_s, const double* __restrict__ wsum, int widx,
    const float* __restrict__ Fbuf, float* __restrict__ Out) {
  const int tid = threadIdx.x;
  const int m0 = blockIdx.y * 128, n0 = blockIdx.x * 128;
  __shared__ __align__(16) u16 As[128 * 32];  // linear, 64B per row
  __shared__ __align__(16) u16 Bs[128 * 32];
  float wscale = (float)fmax(wsum[widx] * (1.0 / (double)WELEM), 1e-5);

  const int wave = tid >> 6, lane = tid & 63;
  const int wm = wave >> 1, wn = wave & 1;
  const int lrow = lane & 15, lk = (lane >> 4) * 8;
  const int srow = lane >> 2, skk = (lane & 3) * 8;  // staging lane map

  f32x4 acc[4][4];
#pragma unroll
  for (int i = 0; i < 4; ++i)
#pragma unroll
    for (int j = 0; j < 4; ++j)
#pragma unroll
      for (int r = 0; r < 4; ++r) acc[i][j][r] = 0.0f;

  const u16* Ab = Aq + (size_t)m0 * HID;
  const u16* Wb = Wq + (size_t)n0 * HID;

  for (int k0 = 0; k0 < HID; k0 += 32) {
#pragma unroll
    for (int c = 0; c < 2; ++c) {
      int chunk = wave * 2 + c;  // wave-uniform: 0..7
      int r = chunk * 16 + srow;
      gl_lds16(&Ab[(size_t)r * HID + k0 + skk], &As[chunk * 512]);
      gl_lds16(&Wb[(size_t)r * HID + k0 + skk], &Bs[chunk * 512]);
    }
    __syncthreads();  // drains vmcnt before barrier
    bf16x8 af[4], bfr[4];
#pragma unroll
    for (int i = 0; i < 4; ++i) {
      af[i] = *(const bf16x8*)&As[(wm * 64 + i * 16 + lrow) * 32 + lk];
      bfr[i] = *(const bf16x8*)&Bs[(wn * 64 + i * 16 + lrow) * 32 + lk];
    }
#pragma unroll
    for (int i = 0; i < 4; ++i)
#pragma unroll
      for (int j = 0; j < 4; ++j)
        acc[i][j] = __builtin_amdgcn_mfma_f32_16x16x32_bf16(af[i], bfr[j],
                                                            acc[i][j], 0, 0, 0);
    __syncthreads();  // LDS reads done before next stage overwrites
  }

#pragma unroll
  for (int i = 0; i < 4; ++i) {
    int rbase = m0 + wm * 64 + i * 16 + (lane >> 4) * 4;
#pragma unroll
    for (int j = 0; j < 4; ++j) {
      int col = n0 + wn * 64 + j * 16 + lrow;
#pragma unroll
      for (int r = 0; r < 4; ++r) {
        int row = rbase + r;
        float v = acc[i][j][r] * inv_s[row] * wscale;
        size_t oidx = (size_t)row * HID + col;
        if (MODE == 0) {
          Out[oidx] = sigm(v);
        } else if (MODE == 1) {
          float f = Fbuf[oidx];
          Out[oidx] = v * sigm(v) * (1.0f - f);
        } else {
          Out[oidx] = v;
        }
      }
    }
  }
}

// ---------------- K5: chunked parallel scan h = f*h + i -------------------
// pass 1: per-chunk local scan (h0=0) + chunk f-product
__global__ __launch_bounds__(256) void scan1_kernel(
    const float* __restrict__ F, float* __restrict__ IO, float* __restrict__ P,
    float* __restrict__ H) {
  int c = blockIdx.x * 256 + threadIdx.x;  // channel 0..4095
  int q = blockIdx.y;                      // chunk
  size_t base =
      (size_t)(c >> 11) * TT * HID + (c & 2047) + (size_t)q * CL * HID;
  float h = 0.0f, p = 1.0f;
#pragma unroll 4
  for (int t = 0; t < CL; ++t) {
    size_t idx = base + (size_t)t * HID;
    float f = F[idx];
    h = fmaf(f, h, IO[idx]);
    p *= f;
    IO[idx] = h;
  }
  P[q * NCH + c] = p;
  H[q * NCH + c] = h;
}

// pass 2: serial combine of the NC chunk aggregates per channel
__global__ __launch_bounds__(256) void scan2_kernel(
    const float* __restrict__ P, const float* __restrict__ H,
    float* __restrict__ Ini) {
  int c = blockIdx.x * 256 + threadIdx.x;
  float carry = 0.0f;
#pragma unroll
  for (int q = 0; q < NC; ++q) {
    Ini[q * NCH + c] = carry;
    carry = fmaf(P[q * NCH + c], carry, H[q * NCH + c]);
  }
}

// pass 3: h_t += (prod_{s<=t} f_s) * h_chunk_init
__global__ __launch_bounds__(256) void scan3_kernel(
    const float* __restrict__ F, const float* __restrict__ Ini,
    float* __restrict__ IO) {
  int c = blockIdx.x * 256 + threadIdx.x;
  int q = blockIdx.y + 1;  // chunk 0 has h0 = 0
  float h0 = Ini[q * NCH + c];
  if (h0 == 0.0f) return;
  size_t base =
      (size_t)(c >> 11) * TT * HID + (c & 2047) + (size_t)q * CL * HID;
  float p = 1.0f;
#pragma unroll 4
  for (int t = 0; t < CL; ++t) {
    size_t idx = base + (size_t)t * HID;
    p *= F[idx];
    IO[idx] = fmaf(p, h0, IO[idx]);
  }
}

// ---------------- K6: fused  o=rms(g)*o*sigm(o)  ->  rms(o,n_o)+quant -----
__global__ __launch_bounds__(256) void combine_quant_kernel(
    const float* __restrict__ G, const float* __restrict__ gnw,
    const float* __restrict__ O, const float* __restrict__ nw,
    u16* __restrict__ Xq, float* __restrict__ inv_s) {
  int tok = blockIdx.x;
  int tid = threadIdx.x;
  int c0 = tid * 8;
  const float* grow = G + (size_t)tok * HID;
  const float* orow = O + (size_t)tok * HID;
  float g[8], o[8];
  *(float4*)&g[0] = *(const float4*)&grow[c0];
  *(float4*)&g[4] = *(const float4*)&grow[c0 + 4];
  *(float4*)&o[0] = *(const float4*)&orow[c0];
  *(float4*)&o[4] = *(const float4*)&orow[c0 + 4];
  __shared__ float sh[4];
  // rms(g, 1e-5)
  float ss = 0.0f;
#pragma unroll
  for (int j = 0; j < 8; ++j) ss += g[j] * g[j];
  float v = wred_sum(ss);
  if ((tid & 63) == 0) sh[tid >> 6] = v;
  __syncthreads();
  float tot = (sh[0] + sh[1]) + (sh[2] + sh[3]);
  float rstd_g = (float)(1.0 / sqrt((double)(tot * (1.0f / HID)) + 1e-5));
  float on[8];
  float ss2 = 0.0f;
#pragma unroll
  for (int j = 0; j < 8; ++j) {
    on[j] = g[j] * rstd_g * gnw[c0 + j] * o[j] * sigm(o[j]);
    ss2 += on[j] * on[j];
  }
  __syncthreads();
  // rms(o_new, 1e-8)
  v = wred_sum(ss2);
  if ((tid & 63) == 0) sh[tid >> 6] = v;
  __syncthreads();
  float tot2 = (sh[0] + sh[1]) + (sh[2] + sh[3]);
  float rstd_o = (float)(1.0 / sqrt((double)(tot2 * (1.0f / HID)) + 1e-8));
  float y[8];
  float amax = 0.0f;
#pragma unroll
  for (int j = 0; j < 8; ++j) {
    y[j] = on[j] * rstd_o * nw[c0 + j];
    amax = fmaxf(amax, fabsf(y[j]));
  }
  __syncthreads();
  v = wred_max(amax);
  if ((tid & 63) == 0) sh[tid >> 6] = v;
  __syncthreads();
  float am = fmaxf(fmaxf(fmaxf(sh[0], sh[1]), fmaxf(sh[2], sh[3])), 1e-5f);
  float s = 127.0f / am;
  u16 q[8];
#pragma unroll
  for (int j = 0; j < 8; ++j) {
    float qq = rintf(y[j] * s);
    qq = fminf(fmaxf(qq, -128.0f), 127.0f);
    q[j] = f2bf(qq);
  }
  *(ushort4*)&Xq[(size_t)tok * HID + c0] = make_ushort4(q[0], q[1], q[2], q[3]);
  *(ushort4*)&Xq[(size_t)tok * HID + c0 + 4] =
      make_ushort4(q[4], q[5], q[6], q[7]);
  if (tid == 0) inv_s[tok] = am * (1.0f / 127.0f);
}

extern "C" void kernel_launch(void* const* d_in, const int* in_sizes, int n_in,
                              void* d_out, int out_size, void* d_ws,
                              size_t ws_size, hipStream_t stream) {
  const float* hs = (const float*)d_in[0];
  const float* w_i = (const float*)d_in[1];
  const float* w_f = (const float*)d_in[2];
  const float* w_g = (const float*)d_in[3];
  const float* w_o = (const float*)d_in[4];
  const float* n_i = (const float*)d_in[5];
  const float* n_f = (const float*)d_in[6];
  const float* n_g = (const float*)d_in[7];
  const float* n_o = (const float*)d_in[8];
  const float* gn_w = (const float*)d_in[9];
  float* Out = (float*)d_out;

  char* ws = (char*)d_ws;
  // layout: WQb 8.4MB | XQ 16.8MB | F 33.5MB | invs 16KB | wsum | P/H/Ini 1.5MB
  u16* WQb = (u16*)ws;
  u16* XQ = (u16*)(ws + 8388608);
  float* F = (float*)(ws + 25165824);
  float* G = F;  // alias: F dead after scan3, G computed after
  float* invs = (float*)(ws + 58720256);
  double* wsum = (double*)(ws + 58736640);
  float* scanP = (float*)(ws + 58737664);
  float* scanH = (float*)(ws + 59261952);
  float* scanI = (float*)(ws + 59786240);

  hipMemsetAsync(wsum, 0, 4 * sizeof(double), stream);
  absmean_kernel<<<2048, 256, 0, stream>>>(w_i, w_f, w_g, w_o, wsum);

  dim3 ggrid(HID / 128, TOKENS / 128);

  // f = sigmoid(bitlinear(hs, w_f, n_f))
  wquant_kernel<<<2048, 256, 0, stream>>>(w_f, wsum, 1, WQb);
  rmsquant_kernel<<<TOKENS, 256, 0, stream>>>(hs, n_f, XQ, invs);
  gemm_kernel<0><<<ggrid, 256, 0, stream>>>(XQ, WQb, invs, wsum, 1, nullptr, F);

  // i = silu(bitlinear(hs, w_i, n_i)) * (1 - f)   -> Out
  wquant_kernel<<<2048, 256, 0, stream>>>(w_i, wsum, 0, WQb);
  rmsquant_kernel<<<TOKENS, 256, 0, stream>>>(hs, n_i, XQ, invs);
  gemm_kernel<1><<<ggrid, 256, 0, stream>>>(XQ, WQb, invs, wsum, 0, F, Out);

  // o_t = f_t * o_{t-1} + i_t   (in-place in Out), chunked parallel scan
  scan1_kernel<<<dim3(NCH / 256, NC), 256, 0, stream>>>(F, Out, scanP, scanH);
  scan2_kernel<<<NCH / 256, 256, 0, stream>>>(scanP, scanH, scanI);
  scan3_kernel<<<dim3(NCH / 256, NC - 1), 256, 0, stream>>>(F, scanI, Out);

  // g = bitlinear(hs, w_g, n_g)  -> G (aliases F)
  wquant_kernel<<<2048, 256, 0, stream>>>(w_g, wsum, 2, WQb);
  rmsquant_kernel<<<TOKENS, 256, 0, stream>>>(hs, n_g, XQ, invs);
  gemm_kernel<2><<<ggrid, 256, 0, stream>>>(XQ, WQb, invs, wsum, 2, nullptr, G);

  // fused: o = rms(g)*o*sigm(o); then rms(o, n_o) + act-quant -> XQ
  combine_quant_kernel<<<TOKENS, 256, 0, stream>>>(G, gn_w, Out, n_o, XQ, invs);

  // out = bitlinear(o, w_o, n_o)
  wquant_kernel<<<2048, 256, 0, stream>>>(w_o, wsum, 3, WQb);
  gemm_kernel<2><<<ggrid, 256, 0, stream>>>(XQ, WQb, invs, wsum, 3, nullptr,
                                            Out);
}

// Round 3
// 265.505 us; speedup vs baseline: 1.8539x; 1.3264x over previous
//
#include <hip/hip_runtime.h>
#include <math.h>

#define HID 2048
#define TOKENS 4096   // B*T
#define TT 2048       // T
#define NCH 4096      // B*HID independent scan channels
#define NC 32         // scan chunks along T
#define CL 64         // chunk length = TT/NC
#define WELEM 4194304 // 2048*2048

typedef unsigned short u16;
typedef signed char i8;
typedef int i32x4 __attribute__((ext_vector_type(4)));

__device__ inline float sigm(float x) { return 1.0f / (1.0f + expf(-x)); }

__device__ inline float wred_sum(float v) {
#pragma unroll
  for (int o = 32; o > 0; o >>= 1) v += __shfl_down(v, o);
  return v;
}
__device__ inline float wred_max(float v) {
#pragma unroll
  for (int o = 32; o > 0; o >>= 1) v = fmaxf(v, __shfl_down(v, o));
  return v;
}
__device__ inline double wred_sumd(double v) {
#pragma unroll
  for (int o = 32; o > 0; o >>= 1) v += __shfl_down(v, o);
  return v;
}

// async global->LDS, 16B per lane; LDS dest = wave-uniform base + lane*16
__device__ __forceinline__ void gl_lds16(const void* g, void* l) {
  __builtin_amdgcn_global_load_lds(
      (__attribute__((address_space(1))) void*)(void*)g,
      (__attribute__((address_space(3))) void*)l, 16, 0, 0);
}

__device__ __forceinline__ int pack8(const int* qi) {
  return (qi[0] & 255) | ((qi[1] & 255) << 8) | ((qi[2] & 255) << 16)
       | ((qi[3] & 255) << 24);
}

// ---------------- K1: mean(|w|) for the 4 weights, f64 accumulation -------
__global__ __launch_bounds__(256) void absmean_kernel(
    const float* __restrict__ w0, const float* __restrict__ w1,
    const float* __restrict__ w2, const float* __restrict__ w3,
    double* __restrict__ wsum) {
  int widx = blockIdx.x >> 9;
  int blk = blockIdx.x & 511;
  const float* w = widx == 0 ? w0 : widx == 1 ? w1 : widx == 2 ? w2 : w3;
  size_t base = (size_t)blk * 8192;
  double acc = 0.0;
#pragma unroll
  for (int r = 0; r < 8; ++r) {
    float4 v = *(const float4*)&w[base + (size_t)(r * 256 + threadIdx.x) * 4];
    acc += (double)fabsf(v.x) + (double)fabsf(v.y) + (double)fabsf(v.z) +
           (double)fabsf(v.w);
  }
  acc = wred_sumd(acc);
  __shared__ double sh[4];
  int tid = threadIdx.x;
  if ((tid & 63) == 0) sh[tid >> 6] = acc;
  __syncthreads();
  if (tid == 0) atomicAdd(&wsum[widx], (sh[0] + sh[1]) + (sh[2] + sh[3]));
}

// ---------------- K2: ternary-quantize one weight matrix to int8 ----------
__global__ __launch_bounds__(256) void wquant_kernel(
    const float* __restrict__ w, const double* __restrict__ wsum, int widx,
    i8* __restrict__ wq) {
  double mean = wsum[widx] * (1.0 / (double)WELEM);
  float s = (float)(1.0 / fmax(mean, 1e-5));
  size_t base = (size_t)blockIdx.x * 2048 + (size_t)threadIdx.x * 8;
  float4 va = *(const float4*)&w[base];
  float4 vb = *(const float4*)&w[base + 4];
  float vv[8] = {va.x, va.y, va.z, va.w, vb.x, vb.y, vb.z, vb.w};
  int qi[8];
#pragma unroll
  for (int j = 0; j < 8; ++j) {
    float q1 = rintf(vv[j] * s);
    q1 = fminf(fmaxf(q1, -1.0f), 1.0f);
    qi[j] = (int)q1;
  }
  *(int2*)&wq[base] = make_int2(pack8(qi), pack8(qi + 4));
}

// ---------------- K3: per-token RMSNorm + 8-bit fake quant -> int8 --------
__global__ __launch_bounds__(256) void rmsquant_kernel(
    const float* __restrict__ X, const float* __restrict__ nw,
    i8* __restrict__ Xq, float* __restrict__ inv_s) {
  int tok = blockIdx.x;
  int tid = threadIdx.x;
  const float* xrow = X + (size_t)tok * HID;
  int c0 = tid * 8;
  float x[8];
  *(float4*)&x[0] = *(const float4*)&xrow[c0];
  *(float4*)&x[4] = *(const float4*)&xrow[c0 + 4];
  float ss = 0.0f;
#pragma unroll
  for (int j = 0; j < 8; ++j) ss += x[j] * x[j];
  __shared__ float sh[4];
  float v = wred_sum(ss);
  if ((tid & 63) == 0) sh[tid >> 6] = v;
  __syncthreads();
  float tot = (sh[0] + sh[1]) + (sh[2] + sh[3]);
  float rstd = (float)(1.0 / sqrt((double)(tot * (1.0f / HID)) + 1e-8));
  float y[8];
  float amax = 0.0f;
#pragma unroll
  for (int j = 0; j < 8; ++j) {
    y[j] = x[j] * rstd * nw[c0 + j];
    amax = fmaxf(amax, fabsf(y[j]));
  }
  __syncthreads();
  v = wred_max(amax);
  if ((tid & 63) == 0) sh[tid >> 6] = v;
  __syncthreads();
  float am = fmaxf(fmaxf(fmaxf(sh[0], sh[1]), fmaxf(sh[2], sh[3])), 1e-5f);
  float s = 127.0f / am;
  int qi[8];
#pragma unroll
  for (int j = 0; j < 8; ++j) {
    float qq = rintf(y[j] * s);
    qq = fminf(fmaxf(qq, -128.0f), 127.0f);
    qi[j] = (int)qq;
  }
  *(int2*)&Xq[(size_t)tok * HID + c0] = make_int2(pack8(qi), pack8(qi + 4));
  if (tid == 0) inv_s[tok] = am * (1.0f / 127.0f);
}

// ---------------- K4: i8 MFMA GEMM, dbuf prefetch + swizzled LDS ----------
// out[m,n] = sum_k A[m,k]*W[n,k]; i32 accumulate (exact).
// MODE 0: out = sigmoid(v); MODE 1: out = v*sigm(v)*(1-F); MODE 2: out = v
// LDS tile: [128 rows][64B], physical 16B-slot sp holds logical slot
// sp ^ ((row>>1)&3)  (inverse-swizzled global source, linear LDS dest).
template <int MODE>
__global__ __launch_bounds__(256) void gemm_kernel(
    const i8* __restrict__ Aq, const i8* __restrict__ Wq,
    const float* __restrict__ inv_s, const double* __restrict__ wsum, int widx,
    const float* __restrict__ Fbuf, float* __restrict__ Out) {
  const int tid = threadIdx.x;
  // XCD-aware bijective swizzle: 512 blocks, 64 consecutive per XCD
  const int lid = blockIdx.x;
  const int swz = (lid & 7) * 64 + (lid >> 3);
  const int n0 = (swz & 15) * 128;  // 16 n-tiles (HID/128)
  const int m0 = (swz >> 4) * 128;  // 32 m-tiles (TOKENS/128)

  __shared__ __align__(16) i8 As[2][128 * 64];
  __shared__ __align__(16) i8 Bs[2][128 * 64];
  float wscale = (float)fmax(wsum[widx] * (1.0 / (double)WELEM), 1e-5);

  const int wave = tid >> 6, lane = tid & 63;
  const int wm = wave >> 1, wn = wave & 1;
  const int lrow = lane & 15;
  const int ksel = lane >> 4;                 // k-quarter 0..3
  const int gr = (lrow >> 1) & 3;             // read-side swizzle
  // staging lane map: row = lane>>2, physical slot p = lane&3
  const int srl = lane >> 2;
  const int sg = (lane >> 3) & 3;             // (srl>>1)&3
  const int skoff = ((lane & 3) ^ sg) << 4;   // inverse-swizzled k-byte

  const i8* Ab = Aq + (size_t)m0 * HID;
  const i8* Wb = Wq + (size_t)n0 * HID;

  i32x4 acc[4][4];
#pragma unroll
  for (int i = 0; i < 4; ++i)
#pragma unroll
    for (int j = 0; j < 4; ++j)
#pragma unroll
      for (int r = 0; r < 4; ++r) acc[i][j][r] = 0;

#define STAGE(buf, k0)                                                     \
  {                                                                        \
    _Pragma("unroll") for (int c = 0; c < 2; ++c) {                        \
      int chunk = wave * 2 + c;                                            \
      int row = chunk * 16 + srl;                                          \
      gl_lds16(&Ab[(size_t)row * HID + (k0) + skoff], &As[buf][chunk * 1024]); \
      gl_lds16(&Wb[(size_t)row * HID + (k0) + skoff], &Bs[buf][chunk * 1024]); \
    }                                                                      \
  }

  STAGE(0, 0)
  __syncthreads();
  int cur = 0;
  const int NT = HID / 64;  // 32 K-steps
  for (int kt = 0; kt < NT; ++kt) {
    if (kt + 1 < NT) STAGE(cur ^ 1, (kt + 1) * 64)
    i32x4 af[4], bfr[4];
#pragma unroll
    for (int i = 0; i < 4; ++i) {
      int ra = wm * 64 + i * 16 + lrow;
      int rb = wn * 64 + i * 16 + lrow;
      af[i] = *(const i32x4*)&As[cur][ra * 64 + ((ksel ^ gr) << 4)];
      bfr[i] = *(const i32x4*)&Bs[cur][rb * 64 + ((ksel ^ gr) << 4)];
    }
#pragma unroll
    for (int i = 0; i < 4; ++i)
#pragma unroll
      for (int j = 0; j < 4; ++j)
        acc[i][j] = __builtin_amdgcn_mfma_i32_16x16x64_i8(af[i], bfr[j],
                                                          acc[i][j], 0, 0, 0);
    __syncthreads();  // drains prefetch vmcnt + protects LDS reuse
    cur ^= 1;
  }
#undef STAGE

#pragma unroll
  for (int i = 0; i < 4; ++i) {
    int rbase = m0 + wm * 64 + i * 16 + (lane >> 4) * 4;
#pragma unroll
    for (int j = 0; j < 4; ++j) {
      int col = n0 + wn * 64 + j * 16 + lrow;
#pragma unroll
      for (int r = 0; r < 4; ++r) {
        int row = rbase + r;
        float v = (float)acc[i][j][r] * inv_s[row] * wscale;
        size_t oidx = (size_t)row * HID + col;
        if (MODE == 0) {
          Out[oidx] = sigm(v);
        } else if (MODE == 1) {
          float f = Fbuf[oidx];
          Out[oidx] = v * sigm(v) * (1.0f - f);
        } else {
          Out[oidx] = v;
        }
      }
    }
  }
}

// ---------------- K5: chunked parallel scan h = f*h + i -------------------
__global__ __launch_bounds__(256) void scan1_kernel(
    const float* __restrict__ F, float* __restrict__ IO, float* __restrict__ P,
    float* __restrict__ H) {
  int c = blockIdx.x * 256 + threadIdx.x;
  int q = blockIdx.y;
  size_t base =
      (size_t)(c >> 11) * TT * HID + (c & 2047) + (size_t)q * CL * HID;
  float h = 0.0f, p = 1.0f;
#pragma unroll 4
  for (int t = 0; t < CL; ++t) {
    size_t idx = base + (size_t)t * HID;
    float f = F[idx];
    h = fmaf(f, h, IO[idx]);
    p *= f;
    IO[idx] = h;
  }
  P[q * NCH + c] = p;
  H[q * NCH + c] = h;
}

__global__ __launch_bounds__(256) void scan2_kernel(
    const float* __restrict__ P, const float* __restrict__ H,
    float* __restrict__ Ini) {
  int c = blockIdx.x * 256 + threadIdx.x;
  float carry = 0.0f;
#pragma unroll
  for (int q = 0; q < NC; ++q) {
    Ini[q * NCH + c] = carry;
    carry = fmaf(P[q * NCH + c], carry, H[q * NCH + c]);
  }
}

__global__ __launch_bounds__(256) void scan3_kernel(
    const float* __restrict__ F, const float* __restrict__ Ini,
    float* __restrict__ IO) {
  int c = blockIdx.x * 256 + threadIdx.x;
  int q = blockIdx.y + 1;
  float h0 = Ini[q * NCH + c];
  if (h0 == 0.0f) return;
  size_t base =
      (size_t)(c >> 11) * TT * HID + (c & 2047) + (size_t)q * CL * HID;
  float p = 1.0f;
#pragma unroll 4
  for (int t = 0; t < CL; ++t) {
    size_t idx = base + (size_t)t * HID;
    p *= F[idx];
    IO[idx] = fmaf(p, h0, IO[idx]);
  }
}

// ---------------- K6: fused  o=rms(g)*o*sigm(o)  ->  rms(o,n_o)+quant -----
__global__ __launch_bounds__(256) void combine_quant_kernel(
    const float* __restrict__ G, const float* __restrict__ gnw,
    const float* __restrict__ O, const float* __restrict__ nw,
    i8* __restrict__ Xq, float* __restrict__ inv_s) {
  int tok = blockIdx.x;
  int tid = threadIdx.x;
  int c0 = tid * 8;
  const float* grow = G + (size_t)tok * HID;
  const float* orow = O + (size_t)tok * HID;
  float g[8], o[8];
  *(float4*)&g[0] = *(const float4*)&grow[c0];
  *(float4*)&g[4] = *(const float4*)&grow[c0 + 4];
  *(float4*)&o[0] = *(const float4*)&orow[c0];
  *(float4*)&o[4] = *(const float4*)&orow[c0 + 4];
  __shared__ float sh[4];
  float ss = 0.0f;
#pragma unroll
  for (int j = 0; j < 8; ++j) ss += g[j] * g[j];
  float v = wred_sum(ss);
  if ((tid & 63) == 0) sh[tid >> 6] = v;
  __syncthreads();
  float tot = (sh[0] + sh[1]) + (sh[2] + sh[3]);
  float rstd_g = (float)(1.0 / sqrt((double)(tot * (1.0f / HID)) + 1e-5));
  float on[8];
  float ss2 = 0.0f;
#pragma unroll
  for (int j = 0; j < 8; ++j) {
    on[j] = g[j] * rstd_g * gnw[c0 + j] * o[j] * sigm(o[j]);
    ss2 += on[j] * on[j];
  }
  __syncthreads();
  v = wred_sum(ss2);
  if ((tid & 63) == 0) sh[tid >> 6] = v;
  __syncthreads();
  float tot2 = (sh[0] + sh[1]) + (sh[2] + sh[3]);
  float rstd_o = (float)(1.0 / sqrt((double)(tot2 * (1.0f / HID)) + 1e-8));
  float y[8];
  float amax = 0.0f;
#pragma unroll
  for (int j = 0; j < 8; ++j) {
    y[j] = on[j] * rstd_o * nw[c0 + j];
    amax = fmaxf(amax, fabsf(y[j]));
  }
  __syncthreads();
  v = wred_max(amax);
  if ((tid & 63) == 0) sh[tid >> 6] = v;
  __syncthreads();
  float am = fmaxf(fmaxf(fmaxf(sh[0], sh[1]), fmaxf(sh[2], sh[3])), 1e-5f);
  float s = 127.0f / am;
  int qi[8];
#pragma unroll
  for (int j = 0; j < 8; ++j) {
    float qq = rintf(y[j] * s);
    qq = fminf(fmaxf(qq, -128.0f), 127.0f);
    qi[j] = (int)qq;
  }
  *(int2*)&Xq[(size_t)tok * HID + c0] = make_int2(pack8(qi), pack8(qi + 4));
  if (tid == 0) inv_s[tok] = am * (1.0f / 127.0f);
}

extern "C" void kernel_launch(void* const* d_in, const int* in_sizes, int n_in,
                              void* d_out, int out_size, void* d_ws,
                              size_t ws_size, hipStream_t stream) {
  const float* hs = (const float*)d_in[0];
  const float* w_i = (const float*)d_in[1];
  const float* w_f = (const float*)d_in[2];
  const float* w_g = (const float*)d_in[3];
  const float* w_o = (const float*)d_in[4];
  const float* n_i = (const float*)d_in[5];
  const float* n_f = (const float*)d_in[6];
  const float* n_g = (const float*)d_in[7];
  const float* n_o = (const float*)d_in[8];
  const float* gn_w = (const float*)d_in[9];
  float* Out = (float*)d_out;

  char* ws = (char*)d_ws;
  // layout: WQb i8 4.2MB | XQ i8 8.4MB | F f32 33.5MB | invs | wsum | scan
  i8* WQb = (i8*)ws;
  i8* XQ = (i8*)(ws + 4194304);
  float* F = (float*)(ws + 12582912);
  float* G = F;  // alias: F dead after scan3, G computed after
  float* invs = (float*)(ws + 46137344);
  double* wsum = (double*)(ws + 46153728);
  float* scanP = (float*)(ws + 46153792);
  float* scanH = (float*)(ws + 46678080);
  float* scanI = (float*)(ws + 47202368);

  hipMemsetAsync(wsum, 0, 4 * sizeof(double), stream);
  absmean_kernel<<<2048, 256, 0, stream>>>(w_i, w_f, w_g, w_o, wsum);

  const int ggrid = (HID / 128) * (TOKENS / 128);  // 512 blocks

  // f = sigmoid(bitlinear(hs, w_f, n_f))
  wquant_kernel<<<2048, 256, 0, stream>>>(w_f, wsum, 1, WQb);
  rmsquant_kernel<<<TOKENS, 256, 0, stream>>>(hs, n_f, XQ, invs);
  gemm_kernel<0><<<ggrid, 256, 0, stream>>>(XQ, WQb, invs, wsum, 1, nullptr, F);

  // i = silu(bitlinear(hs, w_i, n_i)) * (1 - f)   -> Out
  wquant_kernel<<<2048, 256, 0, stream>>>(w_i, wsum, 0, WQb);
  rmsquant_kernel<<<TOKENS, 256, 0, stream>>>(hs, n_i, XQ, invs);
  gemm_kernel<1><<<ggrid, 256, 0, stream>>>(XQ, WQb, invs, wsum, 0, F, Out);

  // o_t = f_t * o_{t-1} + i_t   (in-place in Out), chunked parallel scan
  scan1_kernel<<<dim3(NCH / 256, NC), 256, 0, stream>>>(F, Out, scanP, scanH);
  scan2_kernel<<<NCH / 256, 256, 0, stream>>>(scanP, scanH, scanI);
  scan3_kernel<<<dim3(NCH / 256, NC - 1), 256, 0, stream>>>(F, scanI, Out);

  // g = bitlinear(hs, w_g, n_g)  -> G (aliases F)
  wquant_kernel<<<2048, 256, 0, stream>>>(w_g, wsum, 2, WQb);
  rmsquant_kernel<<<TOKENS, 256, 0, stream>>>(hs, n_g, XQ, invs);
  gemm_kernel<2><<<ggrid, 256, 0, stream>>>(XQ, WQb, invs, wsum, 2, nullptr, G);

  // fused: o = rms(g)*o*sigm(o); then rms(o, n_o) + act-quant -> XQ
  combine_quant_kernel<<<TOKENS, 256, 0, stream>>>(G, gn_w, Out, n_o, XQ, invs);

  // out = bitlinear(o, w_o, n_o)
  wquant_kernel<<<2048, 256, 0, stream>>>(w_o, wsum, 3, WQb);
  gemm_kernel<2><<<ggrid, 256, 0, stream>>>(XQ, WQb, invs, wsum, 3, nullptr,
                                            Out);
}